// Round 4
// baseline (141.202 us; speedup 1.0000x reference)
//
#include <hip/hip_runtime.h>
#include <math.h>

#define HOP     200
#define NB      32
#define TLEN    480000
#define TLEN4   (TLEN / 4)
#define SEG     20                     // output segments per tile
#define NTILE   (TLEN / HOP / SEG)     // 120 tiles per batch row
#define NTPB    3                      // tiles per persistent block
#define NBLKX   (NTILE / NTPB)         // 40 blocks per batch row
#define NSEGP   (SEG + 6)              // 26 partial segments: [q0-3, q0+SEG+2]
#define NW4     (50 * NSEGP)           // 1300 float4s in the x window
#define DOFF    150                    // Phase-D float4 offset into window (3 segs)

#define DLT  0.00785398163397448f      // 2*pi/800
// cos/sin of k*DLT, k=1..3 (within-float4 angle stepping)
#define C1K  0.99996915760f
#define S1K  0.00785390090f
#define C2K  0.99987663248f
#define S2K  0.01570731731f
#define C3K  0.99972243010f
#define S3K  0.02355976470f
// rotation by 40*DLT = pi/10 (between a thread's successive float4s)
#define C40  0.95105651629515f
#define S40  0.30901699437495f

typedef float floatx4 __attribute__((ext_vector_type(4)));

// LDS-only barrier: waits LDS ordering (lgkmcnt) but deliberately leaves
// global prefetch loads and nontemporal out-stores in flight (vmcnt).
// All cross-thread communication in this kernel is via LDS, so this is
// sufficient; __syncthreads() would drain vmcnt(0) and serialize the
// pipeline. Single asm block so nothing can be scheduled between the
// wait and the barrier.
#define LBAR() asm volatile("s_waitcnt lgkmcnt(0)\n\ts_barrier" ::: "memory")

// Analytic collapse (validated in prior session):
//   out[p] = 0.75*x[t] + A'(q,par) - R'(q,par)*cos(p*DLT - psi)  [+ edge w^2 corr]
//
// R4 structure: persistent blocks, NTPB=3 tiles each, software-pipelined.
// While tile t is computed out of the LDS window, tile t+1's window is
// already streaming into registers (issue-early); the ds_write (write-late)
// happens after Phase D's last LDS read. Barriers are lgkm-only so the
// prefetch stays in flight across the whole compute span -> memory system
// streams continuously instead of alternating with compute (the ~41us
// lockstep plateau of R0-R3). Math identical -> bit-identical output.
__global__ __launch_bounds__(256) void stft_tile(const float* __restrict__ x,
                                                 float* __restrict__ out) {
    __shared__ float4 xw4[NW4];             // 20.8 KB raw x window
    __shared__ float  part[NSEGP][10][6];   // 6.2 KB
    __shared__ float  pg[NSEGP][6];         // 0.6 KB
    __shared__ float4 segc[2][SEG];         // 0.6 KB

    const int b  = blockIdx.y;
    const int t0 = blockIdx.x * NTPB;
    const float* xb = x + (size_t)b * TLEN;
    const float4* xg = (const float4*)xb;

    float4 r[6];

    // issue the 6 coalesced loads of tile t's window into registers
    auto stage_load = [&](int t) {
        const int jg0 = 1000 * t - 150;     // 50*(SEG*t - 3)
#pragma unroll
        for (int i = 0; i < 6; ++i) {
            const int j = (int)threadIdx.x + 256 * i;
            if (j < NW4) {
                const int jg = jg0 + j;
                if (jg < 0) {                       // left edge: splat x[0]
                    const float e = xb[0];
                    r[i] = make_float4(e, e, e, e);
                } else if (jg >= TLEN4) {           // right edge: splat x[T-1]
                    const float e = xb[TLEN - 1];
                    r[i] = make_float4(e, e, e, e);
                } else {
                    r[i] = xg[jg];
                }
            }
        }
    };
    auto stage_write = [&]() {
#pragma unroll
        for (int i = 0; i < 6; ++i) {
            const int j = (int)threadIdx.x + 256 * i;
            if (j < NW4) xw4[j] = r[i];
        }
    };

    // prologue: stage first tile's window
    stage_load(t0);
    stage_write();
    LBAR();

    for (int tt = 0; tt < NTPB; ++tt) {
        const int t  = t0 + tt;
        const int q0 = t * SEG;
        const bool pf = (tt + 1 < NTPB);

        // issue-early: next tile's global loads go in flight NOW; they are
        // consumed (vmcnt-waited) only at stage_write after Phase D.
        if (pf) stage_load(t + 1);

        // ---- Phase A: register-accumulated basis partials (LDS source) ----
        for (int u = threadIdx.x; u < NSEGP * 10; u += 256) {
            const int s = u / 10;
            const int k = u - 10 * s;
            const int g = q0 - 3 + s;           // window segment
            const int gm = (g + 4) & 3;         // t mod 800 phase
            float c0, sn0;
            __sincosf((float)(gm * 200 + 4 * k) * DLT, &sn0, &c0);

            float4 v[5];
#pragma unroll
            for (int i = 0; i < 5; ++i) v[i] = xw4[50 * s + k + 10 * i];

            float p1e = 0.f, p1o = 0.f, pce = 0.f, pco = 0.f, pse = 0.f, pso = 0.f;
#pragma unroll
            for (int i = 0; i < 5; ++i) {
                const float c1 = c0 * C1K - sn0 * S1K, s1 = sn0 * C1K + c0 * S1K;
                const float c2 = c0 * C2K - sn0 * S2K, s2 = sn0 * C2K + c0 * S2K;
                const float c3 = c0 * C3K - sn0 * S3K, s3 = sn0 * C3K + c0 * S3K;
                p1e += v[i].x + v[i].z;             p1o += v[i].y + v[i].w;
                pce += c0 * v[i].x + c2 * v[i].z;   pco += c1 * v[i].y + c3 * v[i].w;
                pse += sn0 * v[i].x + s2 * v[i].z;  pso += s1 * v[i].y + s3 * v[i].w;
                const float cn = c0 * C40 - sn0 * S40;   // advance 40 samples
                sn0 = sn0 * C40 + c0 * S40;  c0 = cn;
            }
            part[s][k][0] = p1e;  part[s][k][1] = p1o;
            part[s][k][2] = pce;  part[s][k][3] = pco;
            part[s][k][4] = pse;  part[s][k][5] = pso;
        }
        LBAR();

        // ---- Phase B: fold 10 sub-partials per segment ----
        for (int u = threadIdx.x; u < NSEGP * 6; u += 256) {
            const int s = u / 6;
            const int c = u - 6 * s;
            float a = 0.f;
#pragma unroll
            for (int k = 0; k < 10; ++k) a += part[s][k][c];
            pg[s][c] = a;
        }
        LBAR();

        // ---- Phase C: per-(segment,parity) trig constants, masked frames ----
        if (threadIdx.x < 2 * SEG) {
            const int par = threadIdx.x & 1;
            const int ql  = threadIdx.x >> 1;
            const int q   = q0 + ql;
            float A = 0.f, C = 0.f, D = 0.f;
#pragma unroll
            for (int df = -1; df <= 2; ++df) {
                const int f = q + df;
                if (f < 0 || f > 2400) continue;     // boundary frame mask
                const int ls0 = f - q0 + 1;          // local index of g=f-2
                float sp1 = 0.f, spc = 0.f, sps = 0.f;
#pragma unroll
                for (int kk = 0; kk < 4; ++kk) {
                    const float* rec = pg[ls0 + kk];
                    sp1 += rec[par];  spc += rec[2 + par];  sps += rec[4 + par];
                }
                const int fm = f & 3;
                const float tr = (fm == 0) ? spc : (fm == 1) ? sps : (fm == 2) ? -spc : -sps;
                const float S = 0.5f * sp1 + 0.5f * tr;
                A += S;
                if (fm == 0) C += S; else if (fm == 2) C -= S;
                else if (fm == 1) D += S; else D -= S;
            }
            segc[par][ql] = make_float4(A * (1.0f / 1600.0f),
                                        sqrtf(C * C + D * D) * (1.0f / 1600.0f),
                                        atan2f(D, C), 0.f);
        }
        LBAR();

        // ---- Phase D: stream synth, x from LDS, nontemporal stores ----
        const bool headblk = (t == 0);
        const bool tailblk = (t == NTILE - 1);
        floatx4* og4 = (floatx4*)(out + (size_t)b * TLEN + HOP * q0);
        const int pmb = (q0 & 3) * 200 + 400;
        for (int j = threadIdx.x; j < 50 * SEG; j += 256) {
            const float4 xv = xw4[DOFF + j];
            const int sl = j / 50;
            const float4 ce = segc[0][sl];
            const float4 co = segc[1][sl];
            const int pm = (pmb + 4 * j) % 800;
            const float xa[4] = {xv.x, xv.y, xv.z, xv.w};
            float rr[4];
#pragma unroll
            for (int c = 0; c < 4; ++c) {
                const float4 cc = (c & 1) ? co : ce;
                rr[c] = 0.75f * xa[c] + cc.x - cc.y * __cosf((float)(pm + c) * DLT - cc.z);
            }
            if (headblk && sl == 0) {         // missing frame's w^2 term (analytic)
#pragma unroll
                for (int c = 0; c < 4; ++c) {
                    const float wm = 0.5f + 0.5f * __sinf((float)(pm + c) * DLT);
                    rr[c] -= 0.5f * wm * wm * xa[c];
                }
            }
            if (tailblk && sl == SEG - 1) {
#pragma unroll
                for (int c = 0; c < 4; ++c) {
                    const float wm = 0.5f - 0.5f * __sinf((float)(pm + c) * DLT);
                    rr[c] -= 0.5f * wm * wm * xa[c];
                }
            }
            floatx4 rv = {rr[0], rr[1], rr[2], rr[3]};
            __builtin_nontemporal_store(rv, &og4[j]);
        }

        // write-late: drain prefetch into the (now fully-read) window
        if (pf) {
            LBAR();             // all waves done ds_read-ing xw4 for tile t
            stage_write();      // vmcnt wait happens here, after full overlap
            LBAR();             // window visible to all waves for tile t+1
        }
    }
}

extern "C" void kernel_launch(void* const* d_in, const int* in_sizes, int n_in,
                              void* d_out, int out_size, void* d_ws, size_t ws_size,
                              hipStream_t stream) {
    const float* x = (const float*)d_in[0];
    float* out = (float*)d_out;
    stft_tile<<<dim3(NBLKX, NB), dim3(256), 0, stream>>>(x, out);
}

// Round 5
// 128.421 us; speedup vs baseline: 1.0995x; 1.0995x over previous
//
#include <hip/hip_runtime.h>
#include <math.h>

#define HOP     200
#define NB      32
#define TLEN    480000
#define NSEGT   2400                   // 200-sample segments per batch row
#define WSEG    10                     // output segments per WAVE
#define WPS     (WSEG + 6)             // 16 partial segments per wave
#define NWT     (NSEGT / WSEG)         // 240 wave-tiles per batch row
#define WPB     4                      // waves per 256-thread block
#define NBLKX   (NWT / WPB)            // 60 blocks in x

#define DLT  0.00785398163397448f      // 2*pi/800
// cos/sin of k*DLT, k=1..3 (within-float4 angle stepping)
#define C1K  0.99996915760f
#define S1K  0.00785390090f
#define C2K  0.99987663248f
#define S2K  0.01570731731f
#define C3K  0.99972243010f
#define S3K  0.02355976470f
// rotation by 40*DLT = pi/10 (between a thread's successive float4s)
#define C40  0.95105651629515f
#define S40  0.30901699437495f

typedef float floatx4 __attribute__((ext_vector_type(4)));

// Wave-local phase separator: compiler-level memory ordering (clobber) plus
// an lgkm drain. NO s_barrier — each wave is fully autonomous. Correctness:
// all cross-lane traffic is within one wave's private LDS slice; lanes are
// lockstep and the DS unit processes a wave's LDS ops in order.
#define WSYNC() asm volatile("s_waitcnt lgkmcnt(0)" ::: "memory")

// Analytic collapse (validated in prior session):
//   out[p] = 0.75*x[t] + A'(q,par) - R'(q,par)*cos(p*DLT - psi)  [+ edge w^2 corr]
//
// R5 structure: WAVE-AUTONOMOUS tiles. R0-R4 all pinned at ~41us regardless
// of load source (global/registers/LDS) because every version lockstepped
// 4 waves through read -> s_barrier -> compute -> s_barrier -> write; with
// all resident blocks launched together, the chip alternates memory and
// VALU phases instead of overlapping them (memory ~20us + VALU ~9us + slack
// = 41us observed; VALUBusy 24% and hbm 38% both half-idle). Here one wave
// owns a 10-segment tile end-to-end (dependency span is only +-3 segments):
// zero s_barriers, 32 waves/CU at heterogeneous phases, overlap by scheduler.
// Math identical -> bit-identical output.
__global__ __launch_bounds__(256) void stft_wave(const float* __restrict__ x,
                                                 float* __restrict__ out) {
    __shared__ float  part[WPB][WPS][10][6];   // 15.4 KB, wave-private slices
    __shared__ float  pg[WPB][WPS][6];         // 1.5 KB
    __shared__ float4 segc[WPB][2][WSEG];      // 1.3 KB

    const int w    = threadIdx.x >> 6;         // wave id within block
    const int lane = threadIdx.x & 63;
    const int b    = blockIdx.y;
    const int wt   = blockIdx.x * WPB + w;     // global wave-tile id
    const int wq0  = wt * WSEG;                // first output segment
    const float* xb = x + (size_t)b * TLEN;

    // ---- Phase A: basis partials, global-sourced, wave-private LDS sink ----
    for (int u = lane; u < WPS * 10; u += 64) {
        const int s = u / 10;
        const int k = u - 10 * s;
        const int g = wq0 - 3 + s;              // partial segment (may be OOB)
        const int gm = (g + 4) & 3;             // t mod 800 phase
        float c0, sn0;
        __sincosf((float)(gm * 200 + 4 * k) * DLT, &sn0, &c0);

        float4 v[5];
        if (g >= 0 && g <= 2399) {
            const float4* xs = (const float4*)(xb + 200 * g);
#pragma unroll
            for (int i = 0; i < 5; ++i) v[i] = xs[k + 10 * i];
        } else {                                // edge-pad segment: constant x
            const float e = (g < 0) ? xb[0] : xb[TLEN - 1];
#pragma unroll
            for (int i = 0; i < 5; ++i) v[i] = make_float4(e, e, e, e);
        }

        float p1e = 0.f, p1o = 0.f, pce = 0.f, pco = 0.f, pse = 0.f, pso = 0.f;
#pragma unroll
        for (int i = 0; i < 5; ++i) {
            const float c1 = c0 * C1K - sn0 * S1K, s1 = sn0 * C1K + c0 * S1K;
            const float c2 = c0 * C2K - sn0 * S2K, s2 = sn0 * C2K + c0 * S2K;
            const float c3 = c0 * C3K - sn0 * S3K, s3 = sn0 * C3K + c0 * S3K;
            p1e += v[i].x + v[i].z;             p1o += v[i].y + v[i].w;
            pce += c0 * v[i].x + c2 * v[i].z;   pco += c1 * v[i].y + c3 * v[i].w;
            pse += sn0 * v[i].x + s2 * v[i].z;  pso += s1 * v[i].y + s3 * v[i].w;
            const float cn = c0 * C40 - sn0 * S40;   // advance 40 samples
            sn0 = sn0 * C40 + c0 * S40;  c0 = cn;
        }
        part[w][s][k][0] = p1e;  part[w][s][k][1] = p1o;
        part[w][s][k][2] = pce;  part[w][s][k][3] = pco;
        part[w][s][k][4] = pse;  part[w][s][k][5] = pso;
    }
    WSYNC();

    // ---- Phase B: fold 10 sub-partials per segment (within wave) ----
    for (int u = lane; u < WPS * 6; u += 64) {
        const int s = u / 6;
        const int c = u - 6 * s;
        float a = 0.f;
#pragma unroll
        for (int k = 0; k < 10; ++k) a += part[w][s][k][c];
        pg[w][s][c] = a;
    }
    WSYNC();

    // ---- Phase C: per-(segment,parity) trig constants, masked frames ----
    if (lane < 2 * WSEG) {
        const int par = lane & 1;
        const int ql  = lane >> 1;
        const int q   = wq0 + ql;
        float A = 0.f, C = 0.f, D = 0.f;
#pragma unroll
        for (int df = -1; df <= 2; ++df) {
            const int f = q + df;
            if (f < 0 || f > 2400) continue;     // boundary frame mask
            const int ls0 = f - wq0 + 1;         // local pg row of g=f-2
            float sp1 = 0.f, spc = 0.f, sps = 0.f;
#pragma unroll
            for (int kk = 0; kk < 4; ++kk) {
                const float* rec = pg[w][ls0 + kk];
                sp1 += rec[par];  spc += rec[2 + par];  sps += rec[4 + par];
            }
            const int fm = f & 3;
            const float tr = (fm == 0) ? spc : (fm == 1) ? sps : (fm == 2) ? -spc : -sps;
            const float S = 0.5f * sp1 + 0.5f * tr;
            A += S;
            if (fm == 0) C += S; else if (fm == 2) C -= S;
            else if (fm == 1) D += S; else D -= S;
        }
        segc[w][par][ql] = make_float4(A * (1.0f / 1600.0f),
                                       sqrtf(C * C + D * D) * (1.0f / 1600.0f),
                                       atan2f(D, C), 0.f);
    }
    WSYNC();

    // ---- Phase D: stream synth; x re-read global (L2/L3), NT stores ----
    const bool headw = (wq0 == 0);
    const bool tailw = (wq0 + WSEG == NSEGT);
    const float4* xg4 = (const float4*)xb + 50 * wq0;
    floatx4* og4 = (floatx4*)(out + (size_t)b * TLEN) + 50 * wq0;
    const int pmb = (wq0 & 3) * 200 + 400;
    for (int j = lane; j < 50 * WSEG; j += 64) {
        const float4 xv = xg4[j];
        const int sl = j / 50;
        const float4 ce = segc[w][0][sl];
        const float4 co = segc[w][1][sl];
        const int pm = (pmb + 4 * j) % 800;
        const float xa[4] = {xv.x, xv.y, xv.z, xv.w};
        float r[4];
#pragma unroll
        for (int c = 0; c < 4; ++c) {
            const float4 cc = (c & 1) ? co : ce;
            r[c] = 0.75f * xa[c] + cc.x - cc.y * __cosf((float)(pm + c) * DLT - cc.z);
        }
        if (headw && sl == 0) {           // missing frame's w^2 term (analytic)
#pragma unroll
            for (int c = 0; c < 4; ++c) {
                const float wm = 0.5f + 0.5f * __sinf((float)(pm + c) * DLT);
                r[c] -= 0.5f * wm * wm * xa[c];
            }
        }
        if (tailw && sl == WSEG - 1) {
#pragma unroll
            for (int c = 0; c < 4; ++c) {
                const float wm = 0.5f - 0.5f * __sinf((float)(pm + c) * DLT);
                r[c] -= 0.5f * wm * wm * xa[c];
            }
        }
        floatx4 rv = {r[0], r[1], r[2], r[3]};
        __builtin_nontemporal_store(rv, &og4[j]);
    }
}

extern "C" void kernel_launch(void* const* d_in, const int* in_sizes, int n_in,
                              void* d_out, int out_size, void* d_ws, size_t ws_size,
                              hipStream_t stream) {
    const float* x = (const float*)d_in[0];
    float* out = (float*)d_out;
    stft_wave<<<dim3(NBLKX, NB), dim3(256), 0, stream>>>(x, out);
}